// Round 3
// baseline (2069.706 us; speedup 1.0000x reference)
//
#include <hip/hip_runtime.h>

// OctreeMaxUnpool: out[i*8 + c, k] = (indices[i,k] == c) ? data[nempty_idx[i], k] : 0
// num = 500000, C = 64. Output 1.024 GB. Ideal traffic ~1.28 GB -> ~205 us @ 6.3 TB/s.
//
// R6 CORRECTED MEASUREMENT PROBE. R5's in-thread double-pass failed because
// pass 2 rewrote lines still dirty in L2 (write-back merged -> no extra HBM
// traffic, delta -8 us ~ noise). This version runs REPS=5 full passes with a
// grid-wide rotation (i -> i + rep*217883 mod num) so each rep's lines were
// written ~13600 blocks earlier in schedule order -> evicted from 32 MB L2 ->
// 5 genuine HBM write passes of the full 1.024 GB output. All reps write
// IDENTICAL correct values (bijective remap per rep), so the final output is
// exact regardless of inter-block store order (racing identical bytes).
// Purpose: push the kernel past the 650-us harness fills into the top-5 so we
// finally get OUR dispatch's WRITE_SIZE / FETCH_SIZE / hbm_gbps / VALUBusy.
//   Case B (roofline):   kernel row ~850-1100 us, WRITE_SIZE ~5.0e6 KB, ~6 TB/s.
//   Case A' (pathology): kernel row >2000 us, low BW or WRITE_SIZE >> 5e6 KB.

typedef float vfloat4 __attribute__((ext_vector_type(4)));
typedef int   vint4   __attribute__((ext_vector_type(4)));

constexpr int C4 = 16;      // float4s per row (C=64)
constexpr int NCHILD = 8;
constexpr int REPS = 5;     // probe: 5 genuine HBM write passes

__global__ __launch_bounds__(256) void octree_unpool_kernel(
    const vfloat4* __restrict__ data,      // [N, 16] as float4
    const vint4*   __restrict__ indices,   // [num, 16] as int4
    const int*     __restrict__ nempty,    // [num]
    vfloat4*       __restrict__ out,       // [num*8, 16] as float4
    int num)
{
    int t = blockIdx.x * blockDim.x + threadIdx.x;
    int total = num * C4;                 // 8M threads
    if (t >= total) return;

    int i  = t >> 4;        // octant group
    int k4 = t & 15;        // float4 chunk within row

    int off = 217883;       // rotation step; co-prime-ish, ~num/2.3
    while (off >= num) off -= num;

    int io = 0;             // rep * off  (mod num), maintained incrementally
#pragma unroll 1
    for (int rep = 0; rep < REPS; ++rep) {
        int i2 = i + io; if (i2 >= num) i2 -= num;   // bijective remap per rep

        int row = nempty[i2];   // 16 threads share -> 4 distinct addrs/wave

        vint4   idx4 = indices[i2 * C4 + k4];
        vfloat4 d4   = data[row * C4 + k4];

        vfloat4* base = out + (long long)i2 * (NCHILD * C4) + k4;

#pragma unroll
        for (int c = 0; c < NCHILD; ++c) {
            vfloat4 o;
            o.x = (idx4.x == c) ? d4.x : 0.0f;
            o.y = (idx4.y == c) ? d4.y : 0.0f;
            o.z = (idx4.z == c) ? d4.z : 0.0f;
            o.w = (idx4.w == c) ? d4.w : 0.0f;
            base[c * C4] = o;   // full-line-covered streaming store
        }

        io += off; if (io >= num) io -= num;
    }
}

extern "C" void kernel_launch(void* const* d_in, const int* in_sizes, int n_in,
                              void* d_out, int out_size, void* d_ws, size_t ws_size,
                              hipStream_t stream) {
    const vfloat4* data    = (const vfloat4*)d_in[0];
    const vint4*   indices = (const vint4*)  d_in[1];
    const int*     nempty  = (const int*)    d_in[2];
    // d_in[3] = depth (unused)
    vfloat4* out = (vfloat4*)d_out;

    int num = in_sizes[2];                 // 500000
    int total = num * C4;                  // one thread per (i, k4)
    int block = 256;
    int grid = (total + block - 1) / block;

    octree_unpool_kernel<<<grid, block, 0, stream>>>(data, indices, nempty, out, num);
}

// Round 4
// 1151.915 us; speedup vs baseline: 1.7968x; 1.7968x over previous
//
#include <hip/hip_runtime.h>

// OctreeMaxUnpool: out[i*8 + c, k] = (indices[i,k] == c) ? data[nempty_idx[i], k] : 0
// num = 500000, C = 64. Output 1.024 GB; total traffic ~1.25 GB.
//
// R7: single-pass again (R6 probe measured: write amplification 1.00, occupancy
// 89%, VALUBusy 6.9%, BW 4.85 TB/s = 77% of the 6.25-6.3 TB/s the harness fill
// and float4-copy achieve on this chip). Remaining theory for the 23% gap:
// per-instruction store contiguity. Old mapping (thread=(i,k4), loop c) made
// each wave store instruction write 4 scattered 256B segments spanning 32 KB.
// New mapping: ONE WAVE PER i. Lane l = (g=l>>4 -> child group, k4=l&15).
// Two stores/thread at base[co*64 + l]: each store instruction is a fully
// contiguous 1 KB wave write; a 256-thread block writes 32 KB linearly --
// exactly the fill's pattern. Loads idx4/d4 repeat 4x across the wave ->
// merged into one 256B broadcast transaction (same HBM traffic as before).
//   addr check: base + co*64 + l = i*128 + (co*4+g)*16 + k4 = (i*8+c)*16 + k4. OK

typedef float vfloat4 __attribute__((ext_vector_type(4)));
typedef int   vint4   __attribute__((ext_vector_type(4)));

constexpr int C4 = 16;      // float4s per row (C=64)
constexpr int NCHILD = 8;

__global__ __launch_bounds__(256) void octree_unpool_kernel(
    const vfloat4* __restrict__ data,      // [N, 16] as float4
    const vint4*   __restrict__ indices,   // [num, 16] as int4
    const int*     __restrict__ nempty,    // [num]
    vfloat4*       __restrict__ out,       // [num*8, 16] as float4
    int num)
{
    int i = (blockIdx.x * blockDim.x + threadIdx.x) >> 6;   // one wave per i
    if (i >= num) return;
    int l  = threadIdx.x & 63;
    int g  = l >> 4;        // child group: this lane handles children g and g+4
    int k4 = l & 15;        // float4 chunk within row

    int row = nempty[i];                       // wave-uniform broadcast
    vint4   idx4 = indices[i * C4 + k4];       // 4x-replicated -> one 256B txn
    vfloat4 d4   = data[row * C4 + k4];        // 4x-replicated -> one 256B txn

    vfloat4* base = out + (long long)i * (NCHILD * C4);

#pragma unroll
    for (int co = 0; co < 2; ++co) {
        int c = co * 4 + g;
        vfloat4 o;
        o.x = (idx4.x == c) ? d4.x : 0.0f;
        o.y = (idx4.y == c) ? d4.y : 0.0f;
        o.z = (idx4.z == c) ? d4.z : 0.0f;
        o.w = (idx4.w == c) ? d4.w : 0.0f;
        base[co * 64 + l] = o;   // 1 KB fully-contiguous wave store
    }
}

extern "C" void kernel_launch(void* const* d_in, const int* in_sizes, int n_in,
                              void* d_out, int out_size, void* d_ws, size_t ws_size,
                              hipStream_t stream) {
    const vfloat4* data    = (const vfloat4*)d_in[0];
    const vint4*   indices = (const vint4*)  d_in[1];
    const int*     nempty  = (const int*)    d_in[2];
    // d_in[3] = depth (unused)
    vfloat4* out = (vfloat4*)d_out;

    int num = in_sizes[2];                 // 500000
    long long total = (long long)num * 64; // one wave (64 threads) per i
    int block = 256;
    int grid = (int)((total + block - 1) / block);

    octree_unpool_kernel<<<grid, block, 0, stream>>>(data, indices, nempty, out, num);
}

// Round 5
// 1139.925 us; speedup vs baseline: 1.8157x; 1.0105x over previous
//
#include <hip/hip_runtime.h>

// OctreeMaxUnpool: out[i*8 + c, k] = (indices[i,k] == c) ? data[nempty_idx[i], k] : 0
// num = 500000, C = 64. Output 1.024 GB; total traffic ~1.24 GB -> ~198 us @ 6.3 TB/s.
//
// R8: R7 (wave-per-i, 1KB-contiguous wave stores) gave -16.5 us; calibrated
// accounting (R6 probe: harness floor ~900 us) puts the kernel at ~252 us
// = 4.9 TB/s vs 6.29 TB/s proven achievable by the harness fill + float4 copy.
// Last untested lever: the 1.02 GB write stream cycles the 32 MB L2 ~32x per
// launch (write-back), evicting the read working set and mixing writebacks
// into the read schedule. This round: NON-TEMPORAL stores (evict-first) on the
// two contiguous 1KB wave stores. R1 tested nt on the old SCATTERED mapping
// (null) -- with full-line-covered stores nt can't hurt merging, only relieve
// L2 pollution. Single variable vs R7.

typedef float vfloat4 __attribute__((ext_vector_type(4)));
typedef int   vint4   __attribute__((ext_vector_type(4)));

constexpr int C4 = 16;      // float4s per row (C=64)
constexpr int NCHILD = 8;

__global__ __launch_bounds__(256) void octree_unpool_kernel(
    const vfloat4* __restrict__ data,      // [N, 16] as float4
    const vint4*   __restrict__ indices,   // [num, 16] as int4
    const int*     __restrict__ nempty,    // [num]
    vfloat4*       __restrict__ out,       // [num*8, 16] as float4
    int num)
{
    int i = (blockIdx.x * blockDim.x + threadIdx.x) >> 6;   // one wave per i
    if (i >= num) return;
    int l  = threadIdx.x & 63;
    int g  = l >> 4;        // child group: this lane handles children g and g+4
    int k4 = l & 15;        // float4 chunk within row

    int row = nempty[i];                       // wave-uniform broadcast
    vint4   idx4 = indices[i * C4 + k4];       // 4x-replicated -> one 256B txn
    vfloat4 d4   = data[row * C4 + k4];        // 4x-replicated -> one 256B txn

    vfloat4* base = out + (long long)i * (NCHILD * C4);

#pragma unroll
    for (int co = 0; co < 2; ++co) {
        int c = co * 4 + g;
        vfloat4 o;
        o.x = (idx4.x == c) ? d4.x : 0.0f;
        o.y = (idx4.y == c) ? d4.y : 0.0f;
        o.z = (idx4.z == c) ? d4.z : 0.0f;
        o.w = (idx4.w == c) ? d4.w : 0.0f;
        // 1 KB fully-contiguous wave store, evict-first (keep reads in L2)
        __builtin_nontemporal_store(o, base + co * 64 + l);
    }
}

extern "C" void kernel_launch(void* const* d_in, const int* in_sizes, int n_in,
                              void* d_out, int out_size, void* d_ws, size_t ws_size,
                              hipStream_t stream) {
    const vfloat4* data    = (const vfloat4*)d_in[0];
    const vint4*   indices = (const vint4*)  d_in[1];
    const int*     nempty  = (const int*)    d_in[2];
    // d_in[3] = depth (unused)
    vfloat4* out = (vfloat4*)d_out;

    int num = in_sizes[2];                 // 500000
    long long total = (long long)num * 64; // one wave (64 threads) per i
    int block = 256;
    int grid = (int)((total + block - 1) / block);

    octree_unpool_kernel<<<grid, block, 0, stream>>>(data, indices, nempty, out, num);
}